// Round 1
// baseline (1499.718 us; speedup 1.0000x reference)
//
#include <hip/hip_runtime.h>
#include <stdint.h>

// Problem constants (B=8, S=1024, D=1024, K=8192)
#define NROWS 8192   // B*S
#define KCODES 8192
#define DDIM 1024

// d_out flat float32 layout (return order: quantized, indices, loss, logits)
#define Q_OFF    0
#define IDX_OFF  8388608
#define LOSS_OFF 8396800
#define LOG_OFF  8396801   // NOTE: odd -> logits region only 4B-aligned

// Monotone map float -> uint32 preserving order (for packed atomicMin argmin)
__device__ __forceinline__ unsigned int forder(float f) {
  unsigned int u = __float_as_uint(f);
  return (u & 0x80000000u) ? ~u : (u | 0x80000000u);
}

// ---------------------------------------------------------------------------
// Kernel 1: squared row norms of z (rows 0..8191) and codebook (rows 8192..16383)
// ---------------------------------------------------------------------------
__global__ __launch_bounds__(256) void vq_norms(const float* __restrict__ z,
                                                const float* __restrict__ cb,
                                                float* __restrict__ nrm) {
  const int r = blockIdx.x;
  const float* src = (r < NROWS) ? (z + (size_t)r * DDIM)
                                 : (cb + (size_t)(r - NROWS) * DDIM);
  float4 v = reinterpret_cast<const float4*>(src)[threadIdx.x];  // 256*4 = 1024
  float s = v.x * v.x + v.y * v.y + v.z * v.z + v.w * v.w;
  #pragma unroll
  for (int m = 32; m > 0; m >>= 1) s += __shfl_down(s, m, 64);
  __shared__ float red[4];
  if ((threadIdx.x & 63) == 0) red[threadIdx.x >> 6] = s;
  __syncthreads();
  if (threadIdx.x == 0) nrm[r] = red[0] + red[1] + red[2] + red[3];
}

// ---------------------------------------------------------------------------
// Kernel 2: fp32 tiled GEMM, 128x128 tile, 8x8 micro-tile, BK=32.
// Writes logits = 2*z.e - ||z||^2 - ||e||^2 and per-row packed argmin.
// ---------------------------------------------------------------------------
__global__ __launch_bounds__(256, 3) void vq_gemm(const float* __restrict__ z,
                                                  const float* __restrict__ cb,
                                                  const float* __restrict__ nrm,
                                                  unsigned long long* __restrict__ mins,
                                                  float* __restrict__ out) {
  constexpr int BM = 128, BN = 128, BK = 32;
  __shared__ float As[BK][BM];  // As[d][m] = z[n0+m][d0+d]
  __shared__ float Bs[BK][BN];  // Bs[d][k] = cb[k0+k][d0+d]

  const int n0 = blockIdx.y * BM;
  const int k0 = blockIdx.x * BN;
  const int tid = threadIdx.x;           // 0..255
  const int ty = tid >> 4, tx = tid & 15;
  const int r0 = ty * 8, c0 = tx * 8;

  // staging map: per matrix 128 rows x 32 cols; thread -> row tid>>1, 16-col half
  const int lr = tid >> 1;
  const int lc = (tid & 1) * 16;

  float acc[8][8];
  #pragma unroll
  for (int i = 0; i < 8; ++i)
    #pragma unroll
    for (int j = 0; j < 8; ++j) acc[i][j] = 0.f;

  const float* aptr = z + (size_t)(n0 + lr) * DDIM + lc;
  const float* bptr = cb + (size_t)(k0 + lr) * DDIM + lc;

  for (int d0 = 0; d0 < DDIM; d0 += BK) {
    float4 av[4], bv[4];
    #pragma unroll
    for (int q = 0; q < 4; ++q) av[q] = reinterpret_cast<const float4*>(aptr + d0)[q];
    #pragma unroll
    for (int q = 0; q < 4; ++q) bv[q] = reinterpret_cast<const float4*>(bptr + d0)[q];

    __syncthreads();  // previous iteration's readers are done
    #pragma unroll
    for (int q = 0; q < 4; ++q) {
      As[lc + q * 4 + 0][lr] = av[q].x;
      As[lc + q * 4 + 1][lr] = av[q].y;
      As[lc + q * 4 + 2][lr] = av[q].z;
      As[lc + q * 4 + 3][lr] = av[q].w;
      Bs[lc + q * 4 + 0][lr] = bv[q].x;
      Bs[lc + q * 4 + 1][lr] = bv[q].y;
      Bs[lc + q * 4 + 2][lr] = bv[q].z;
      Bs[lc + q * 4 + 3][lr] = bv[q].w;
    }
    __syncthreads();

    #pragma unroll 8
    for (int kk = 0; kk < BK; ++kk) {
      float a[8], b[8];
      *reinterpret_cast<float4*>(&a[0]) = *reinterpret_cast<const float4*>(&As[kk][r0]);
      *reinterpret_cast<float4*>(&a[4]) = *reinterpret_cast<const float4*>(&As[kk][r0 + 4]);
      *reinterpret_cast<float4*>(&b[0]) = *reinterpret_cast<const float4*>(&Bs[kk][c0]);
      *reinterpret_cast<float4*>(&b[4]) = *reinterpret_cast<const float4*>(&Bs[kk][c0 + 4]);
      #pragma unroll
      for (int i = 0; i < 8; ++i)
        #pragma unroll
        for (int j = 0; j < 8; ++j)
          acc[i][j] = fmaf(a[i], b[j], acc[i][j]);
    }
  }

  // Epilogue: distances, logits, per-row argmin
  float zzv[8], eev[8];
  #pragma unroll
  for (int i = 0; i < 8; ++i) zzv[i] = nrm[n0 + r0 + i];
  #pragma unroll
  for (int j = 0; j < 8; ++j) eev[j] = nrm[NROWS + k0 + c0 + j];

  float* logits = out + LOG_OFF;
  #pragma unroll
  for (int i = 0; i < 8; ++i) {
    const int n = n0 + r0 + i;
    unsigned long long best = ~0ull;
    #pragma unroll
    for (int j = 0; j < 8; ++j) {
      const int k = k0 + c0 + j;
      const float dist = fmaf(-2.f, acc[i][j], zzv[i] + eev[j]);
      logits[(size_t)n * KCODES + k] = -dist;  // scalar store (4B-aligned region)
      const unsigned long long p =
          ((unsigned long long)forder(dist) << 32) | (unsigned int)k;
      best = best < p ? best : p;
    }
    // reduce across the 16 lanes sharing this row (tx group); xor<16 stays in group
    #pragma unroll
    for (int m = 1; m < 16; m <<= 1) {
      const unsigned long long o = __shfl_xor(best, m, 64);
      best = best < o ? best : o;
    }
    if (tx == 0) atomicMin(&mins[n], best);  // ties -> smaller k, matches np.argmin
  }
}

// ---------------------------------------------------------------------------
// Kernel 3: finalize — gather quantized rows, write indices (as float) + loss
// ---------------------------------------------------------------------------
__global__ __launch_bounds__(256) void vq_finalize(const float* __restrict__ cb,
                                                   const unsigned long long* __restrict__ mins,
                                                   float* __restrict__ out) {
  const int n = blockIdx.x;
  const unsigned int k = (unsigned int)(mins[n] & 0xFFFFFFFFu);
  const float4* src = reinterpret_cast<const float4*>(cb + (size_t)k * DDIM);
  float4* dst = reinterpret_cast<float4*>(out + (size_t)n * DDIM);
  dst[threadIdx.x] = src[threadIdx.x];  // 256*16B = 4KB row
  if (threadIdx.x == 0) {
    out[IDX_OFF + n] = (float)k;
    if (n == 0) out[LOSS_OFF] = 0.f;
  }
}

// ---------------------------------------------------------------------------
extern "C" void kernel_launch(void* const* d_in, const int* in_sizes, int n_in,
                              void* d_out, int out_size, void* d_ws, size_t ws_size,
                              hipStream_t stream) {
  const float* z  = (const float*)d_in[0];
  const float* cb = (const float*)d_in[1];
  float* out = (float*)d_out;

  // ws layout: [0,64KB) row norms (16384 f32); [64KB,128KB) packed u64 argmins
  float* nrm = (float*)d_ws;
  unsigned long long* mins = (unsigned long long*)((char*)d_ws + 65536);

  hipMemsetAsync((char*)d_ws + 65536, 0xFF, NROWS * sizeof(unsigned long long), stream);
  vq_norms<<<NROWS + KCODES, 256, 0, stream>>>(z, cb, nrm);
  dim3 grid(KCODES / 128, NROWS / 128);
  vq_gemm<<<grid, 256, 0, stream>>>(z, cb, nrm, mins, out);
  vq_finalize<<<NROWS, 256, 0, stream>>>(cb, mins, out);
}

// Round 2
// 318.241 us; speedup vs baseline: 4.7125x; 4.7125x over previous
//
#include <hip/hip_runtime.h>
#include <hip/hip_bf16.h>
#include <stdint.h>

// Problem constants (B=8, S=1024, D=1024, K=8192)
#define NROWS 8192   // B*S
#define KCODES 8192
#define DDIM 1024

// d_out flat float32 layout (return order: quantized, indices, loss, logits)
#define Q_OFF    0
#define IDX_OFF  8388608
#define LOSS_OFF 8396800
#define LOG_OFF  8396801   // odd -> logits region only 4B-aligned

using f32x4  = __attribute__((ext_vector_type(4))) float;
using s16x8  = __attribute__((ext_vector_type(8))) short;

// Monotone map float -> uint32 preserving order (for packed atomicMin argmin)
__device__ __forceinline__ unsigned int forder(float f) {
  unsigned int u = __float_as_uint(f);
  return (u & 0x80000000u) ? ~u : (u | 0x80000000u);
}

__device__ __forceinline__ void gld_lds16(const void* g, void* l) {
  __builtin_amdgcn_global_load_lds((const __attribute__((address_space(1))) unsigned int*)g,
                                   (__attribute__((address_space(3))) unsigned int*)l,
                                   16, 0, 0);
}

// ---------------------------------------------------------------------------
// Kernel 1: fp32 -> bf16 copies of z (rows 0..8191) and codebook (8192..16383)
// into the out[quantized] region (overwritten by the final gather), plus
// exact fp32 squared row norms into ws.
// ---------------------------------------------------------------------------
__global__ __launch_bounds__(256) void vq_convert(const float* __restrict__ z,
                                                  const float* __restrict__ cb,
                                                  __hip_bfloat16* __restrict__ bfbuf,
                                                  float* __restrict__ nrm) {
  const int r = blockIdx.x;
  const float* src = (r < NROWS) ? (z + (size_t)r * DDIM)
                                 : (cb + (size_t)(r - NROWS) * DDIM);
  float4 v = reinterpret_cast<const float4*>(src)[threadIdx.x];  // 256*4 = 1024
  float vv[4] = {v.x, v.y, v.z, v.w};
  ushort4 p;
  unsigned short us[4];
  #pragma unroll
  for (int j = 0; j < 4; ++j) {
    __hip_bfloat16 b = __float2bfloat16(vv[j]);
    __builtin_memcpy(&us[j], &b, 2);
  }
  p.x = us[0]; p.y = us[1]; p.z = us[2]; p.w = us[3];
  reinterpret_cast<ushort4*>(bfbuf + (size_t)r * DDIM)[threadIdx.x] = p;

  float s = vv[0]*vv[0] + vv[1]*vv[1] + vv[2]*vv[2] + vv[3]*vv[3];
  #pragma unroll
  for (int m = 32; m > 0; m >>= 1) s += __shfl_down(s, m, 64);
  __shared__ float red[4];
  if ((threadIdx.x & 63) == 0) red[threadIdx.x >> 6] = s;
  __syncthreads();
  if (threadIdx.x == 0) nrm[r] = red[0] + red[1] + red[2] + red[3];
}

// ---------------------------------------------------------------------------
// Kernel 2: bf16 MFMA GEMM, 128x128 tile, BK=64, 4 waves (each 64x64 out),
// global_load_lds width-16 staging with XOR chunk swizzle (both-sides).
// Writes logits = -(zz + ee - 2*dot) and per-row packed approx argmin.
// ---------------------------------------------------------------------------
__global__ __launch_bounds__(256, 3) void vq_mfma(const __hip_bfloat16* __restrict__ zb,
                                                  const __hip_bfloat16* __restrict__ cbb,
                                                  const float* __restrict__ nrm,
                                                  unsigned long long* __restrict__ mins,
                                                  float* __restrict__ out) {
  __shared__ s16x8 Asv[1024];  // 128 rows x 8 chunks of 8 bf16 (16KB)
  __shared__ s16x8 Bsv[1024];

  const int k0 = blockIdx.x * 128;
  const int n0 = blockIdx.y * 128;
  const int tid = threadIdx.x;
  const int wid = tid >> 6, lane = tid & 63;
  const int wm = wid >> 1, wn = wid & 1;    // wave grid 2x2, wave out = 64x64
  const int l15 = lane & 15, l4 = lane >> 4;

  // staging geometry: slab s = wid*4+q covers rows 8s..8s+7 (1KB per wave-issue)
  const int srow = lane >> 3;          // row within slab
  const int c    = lane & 7;           // LDS 16B chunk within row
  const __hip_bfloat16* ga[4];
  const __hip_bfloat16* gb[4];
  int loff[4];
  #pragma unroll
  for (int q = 0; q < 4; ++q) {
    const int s = wid * 4 + q;
    const int row = s * 8 + srow;
    const int cg = c ^ (row & 7);      // pre-swizzled global chunk
    ga[q] = zb  + (size_t)(n0 + row) * DDIM + cg * 8;
    gb[q] = cbb + (size_t)(k0 + row) * DDIM + cg * 8;
    loff[q] = s * 1024;                // LDS byte offset of slab (wave-uniform)
  }

  f32x4 acc[4][4];
  #pragma unroll
  for (int i = 0; i < 4; ++i)
    #pragma unroll
    for (int j = 0; j < 4; ++j) acc[i][j] = (f32x4){0.f, 0.f, 0.f, 0.f};

  for (int it = 0; it < 16; ++it) {
    const int d0 = it * 64;
    #pragma unroll
    for (int q = 0; q < 4; ++q) {
      gld_lds16(ga[q] + d0, (char*)Asv + loff[q]);
      gld_lds16(gb[q] + d0, (char*)Bsv + loff[q]);
    }
    __syncthreads();  // compiler drains vmcnt before barrier -> tile staged

    #pragma unroll
    for (int ks = 0; ks < 2; ++ks) {
      const int ch = ks * 4 + l4;      // wanted global chunk 0..7
      s16x8 af[4], bf[4];
      #pragma unroll
      for (int f = 0; f < 4; ++f) {
        const int ar = wm * 64 + f * 16 + l15;
        af[f] = Asv[ar * 8 + (ch ^ (ar & 7))];
        const int br = wn * 64 + f * 16 + l15;
        bf[f] = Bsv[br * 8 + (ch ^ (br & 7))];
      }
      #pragma unroll
      for (int fm = 0; fm < 4; ++fm)
        #pragma unroll
        for (int fn = 0; fn < 4; ++fn)
          acc[fm][fn] = __builtin_amdgcn_mfma_f32_16x16x32_bf16(af[fm], bf[fn], acc[fm][fn], 0, 0, 0);
    }
    __syncthreads();  // readers done before next overwrite
  }

  // Epilogue: logits + per-row packed argmin.
  // C/D layout (16x16x32): col = lane&15 (code k), row = (lane>>4)*4 + reg (z-row n)
  float ee[4];
  #pragma unroll
  for (int fn = 0; fn < 4; ++fn) ee[fn] = nrm[NROWS + k0 + wn * 64 + fn * 16 + l15];

  float* logits = out + LOG_OFF;
  #pragma unroll
  for (int fm = 0; fm < 4; ++fm) {
    #pragma unroll
    for (int r = 0; r < 4; ++r) {
      const int n = n0 + wm * 64 + fm * 16 + l4 * 4 + r;
      const float zz = nrm[n];
      unsigned long long best = ~0ull;
      #pragma unroll
      for (int fn = 0; fn < 4; ++fn) {
        const int k = k0 + wn * 64 + fn * 16 + l15;
        const float dist = fmaf(-2.f, acc[fm][fn][r], zz + ee[fn]);
        logits[(size_t)n * KCODES + k] = -dist;
        const unsigned long long p =
            ((unsigned long long)forder(dist) << 32) | (unsigned int)k;
        best = best < p ? best : p;
      }
      #pragma unroll
      for (int mm = 1; mm < 16; mm <<= 1) {
        const unsigned long long o = __shfl_xor(best, mm, 64);
        best = best < o ? best : o;
      }
      if (l15 == 0) atomicMin(&mins[n], best);
    }
  }
}

// ---------------------------------------------------------------------------
// Kernel 3: refine — rescan logits row, collect candidates within MARGIN of
// approx min, recompute exact fp32 distances, pick true argmin (tie -> min k).
// ---------------------------------------------------------------------------
#define MARGIN 12.0f
__global__ __launch_bounds__(256) void vq_refine(const float* __restrict__ z,
                                                 const float* __restrict__ cb,
                                                 const float* __restrict__ nrm,
                                                 const unsigned long long* __restrict__ mins,
                                                 float* __restrict__ out) {
  const int n = blockIdx.x;
  const unsigned long long m = mins[n];
  const unsigned int du = (unsigned int)(m >> 32);
  const float dmin = (du & 0x80000000u) ? __uint_as_float(du & 0x7fffffffu)
                                        : __uint_as_float(~du);
  const float thr = dmin + MARGIN;

  __shared__ int cnt;
  __shared__ int cand[64];
  if (threadIdx.x == 0) cnt = 0;
  __syncthreads();
  const float* lrow = out + LOG_OFF + (size_t)n * KCODES;
  for (int j = threadIdx.x; j < KCODES; j += 256) {
    const float dist = -lrow[j];
    if (dist <= thr) {
      const int p = atomicAdd(&cnt, 1);
      if (p < 64) cand[p] = j;
    }
  }
  __syncthreads();
  const int ncand = min(cnt, 64);

  const float zz = nrm[n];
  const float4 zv = reinterpret_cast<const float4*>(z + (size_t)n * DDIM)[threadIdx.x];
  __shared__ float red[4];
  float bestd = 0.f;
  int bestk = -1;
  for (int ci = 0; ci < ncand; ++ci) {
    const int k = cand[ci];
    const float4 ev = reinterpret_cast<const float4*>(cb + (size_t)k * DDIM)[threadIdx.x];
    float s = zv.x * ev.x + zv.y * ev.y + zv.z * ev.z + zv.w * ev.w;
    #pragma unroll
    for (int mm = 32; mm > 0; mm >>= 1) s += __shfl_down(s, mm, 64);
    if ((threadIdx.x & 63) == 0) red[threadIdx.x >> 6] = s;
    __syncthreads();
    const float dot = red[0] + red[1] + red[2] + red[3];
    const float dist = zz + nrm[NROWS + k] - 2.0f * dot;
    if (bestk < 0 || dist < bestd || (dist == bestd && k < bestk)) {
      bestd = dist; bestk = k;
    }
    __syncthreads();  // protect red before next candidate
  }
  if (threadIdx.x == 0) {
    if (bestk < 0) bestk = (int)(m & 0xFFFFFFFFu);  // unreachable safety
    out[IDX_OFF + n] = (float)bestk;
  }
}

// ---------------------------------------------------------------------------
// Kernel 4: gather quantized rows (overwrites the bf16 staging area), loss.
// ---------------------------------------------------------------------------
__global__ __launch_bounds__(256) void vq_finalize(const float* __restrict__ cb,
                                                   float* __restrict__ out) {
  const int n = blockIdx.x;
  const int k = (int)out[IDX_OFF + n];  // exact for k < 2^24
  const float4* src = reinterpret_cast<const float4*>(cb + (size_t)k * DDIM);
  float4* dst = reinterpret_cast<float4*>(out + (size_t)n * DDIM);
  dst[threadIdx.x] = src[threadIdx.x];
  if (threadIdx.x == 0 && n == 0) out[LOSS_OFF] = 0.f;
}

// ---------------------------------------------------------------------------
extern "C" void kernel_launch(void* const* d_in, const int* in_sizes, int n_in,
                              void* d_out, int out_size, void* d_ws, size_t ws_size,
                              hipStream_t stream) {
  const float* z  = (const float*)d_in[0];
  const float* cb = (const float*)d_in[1];
  float* out = (float*)d_out;

  // ws: [0,64KB) fp32 row norms (16384); [64KB,128KB) packed u64 argmins (8192)
  float* nrm = (float*)d_ws;
  unsigned long long* mins = (unsigned long long*)((char*)d_ws + 65536);

  // bf16 staging lives in the out[quantized] region (exact fit: 2*8192*1024*2B)
  __hip_bfloat16* bfbuf = (__hip_bfloat16*)out;
  const __hip_bfloat16* zbf  = bfbuf;
  const __hip_bfloat16* cbbf = bfbuf + (size_t)NROWS * DDIM;

  hipMemsetAsync((char*)d_ws + 65536, 0xFF, NROWS * sizeof(unsigned long long), stream);
  vq_convert<<<NROWS + KCODES, 256, 0, stream>>>(z, cb, bfbuf, nrm);
  dim3 grid(KCODES / 128, NROWS / 128);
  vq_mfma<<<grid, 256, 0, stream>>>(zbf, cbbf, nrm, mins, out);
  vq_refine<<<NROWS, 256, 0, stream>>>(z, cb, nrm, mins, out);
  vq_finalize<<<NROWS, 256, 0, stream>>>(cb, out);
}

// Round 3
// 278.735 us; speedup vs baseline: 5.3804x; 1.1417x over previous
//
#include <hip/hip_runtime.h>
#include <hip/hip_bf16.h>
#include <stdint.h>

// Problem constants (B=8, S=1024, D=1024, K=8192)
#define NROWS 8192   // B*S
#define KCODES 8192
#define DDIM 1024

// d_out flat float32 layout (return order: quantized, indices, loss, logits)
#define Q_OFF    0
#define IDX_OFF  8388608
#define LOSS_OFF 8396800
#define LOG_OFF  8396801   // odd -> logits region only 4B-aligned

using f32x4  = __attribute__((ext_vector_type(4))) float;
using s16x8  = __attribute__((ext_vector_type(8))) short;

// Monotone map float <-> uint32 preserving order (for atomicMin argmin tables)
__device__ __forceinline__ unsigned int forder(float f) {
  unsigned int u = __float_as_uint(f);
  return (u & 0x80000000u) ? ~u : (u | 0x80000000u);
}
__device__ __forceinline__ float finv(unsigned int u) {
  return (u & 0x80000000u) ? __uint_as_float(u & 0x7fffffffu) : __uint_as_float(~u);
}

__device__ __forceinline__ void gld_lds16(const void* g, void* l) {
  __builtin_amdgcn_global_load_lds((const __attribute__((address_space(1))) unsigned int*)g,
                                   (__attribute__((address_space(3))) unsigned int*)l,
                                   16, 0, 0);
}

// ---------------------------------------------------------------------------
// Kernel 1: fp32 -> bf16 copies of z (rows 0..8191) and codebook (8192..16383)
// into the out[quantized] region (overwritten by the final gather), plus
// exact fp32 squared row norms into ws.
// ---------------------------------------------------------------------------
__global__ __launch_bounds__(256) void vq_convert(const float* __restrict__ z,
                                                  const float* __restrict__ cb,
                                                  __hip_bfloat16* __restrict__ bfbuf,
                                                  float* __restrict__ nrm) {
  const int r = blockIdx.x;
  const float* src = (r < NROWS) ? (z + (size_t)r * DDIM)
                                 : (cb + (size_t)(r - NROWS) * DDIM);
  float4 v = reinterpret_cast<const float4*>(src)[threadIdx.x];  // 256*4 = 1024
  float vv[4] = {v.x, v.y, v.z, v.w};
  ushort4 p;
  unsigned short us[4];
  #pragma unroll
  for (int j = 0; j < 4; ++j) {
    __hip_bfloat16 b = __float2bfloat16(vv[j]);
    __builtin_memcpy(&us[j], &b, 2);
  }
  p.x = us[0]; p.y = us[1]; p.z = us[2]; p.w = us[3];
  reinterpret_cast<ushort4*>(bfbuf + (size_t)r * DDIM)[threadIdx.x] = p;

  float s = vv[0]*vv[0] + vv[1]*vv[1] + vv[2]*vv[2] + vv[3]*vv[3];
  #pragma unroll
  for (int m = 32; m > 0; m >>= 1) s += __shfl_down(s, m, 64);
  __shared__ float red[4];
  if ((threadIdx.x & 63) == 0) red[threadIdx.x >> 6] = s;
  __syncthreads();
  if (threadIdx.x == 0) nrm[r] = red[0] + red[1] + red[2] + red[3];
}

// ---------------------------------------------------------------------------
// Kernel 2: bf16 MFMA GEMM, 256x256 tile, BK=64, 8 waves (2Mx4N, 128x64 each),
// 4-phase-per-K-tile pipeline with counted vmcnt (never 0 in main loop).
// LDS 128KB: per buffer, A/B stored half-major: [half=kstep][256 rows][32 cols]
// with XOR swizzle chunk ^= (row>>1)&3 (both-sides: pre-swizzled global src).
// Writes logits = -(zz + ee - 2*dot) and per-(row, 256-col-block) min table.
// ---------------------------------------------------------------------------
__global__ __launch_bounds__(512, 2) void vq_mfma(const __hip_bfloat16* __restrict__ zb,
                                                  const __hip_bfloat16* __restrict__ cbb,
                                                  const float* __restrict__ nrm,
                                                  unsigned int* __restrict__ gmins,
                                                  float* __restrict__ out) {
  __shared__ s16x8 lds[8192];  // 128 KB. A: chunks [buf*2048 + h*1024 + row*4 + c]; B: +4096

  const int bx = blockIdx.x;            // k-block 0..31
  const int by = blockIdx.y;            // n-block 0..31
  const int k0 = bx * 256, n0 = by * 256;
  const int tid = threadIdx.x;
  const int wid = tid >> 6, lane = tid & 63;
  const int wm = wid >> 2, wn = wid & 3;   // wave grid 2M x 4N; wave out 128x64
  const int l15 = lane & 15, l4 = lane >> 4;

  // --- staging precompute: 2 gld_lds16 per thread per 16KB half-stage ---
  // stage chunk id c = (wid*2+q)*64 + lane; row = c>>2; pos-chunk = c&3;
  // global source is PRE-swizzled: logical chunk = (c&3) ^ ((row>>1)&3)
  const __hip_bfloat16* aS[2];
  const __hip_bfloat16* bS[2];
  int ldst[2];
  #pragma unroll
  for (int q = 0; q < 2; ++q) {
    const int c = (wid * 2 + q) * 64 + lane;
    const int srow = c >> 2;
    const int skcl = (c & 3) ^ ((srow >> 1) & 3);
    ldst[q] = (wid * 2 + q) * 1024;     // byte offset within a 16KB half region
    aS[q] = zb  + (size_t)(n0 + srow) * DDIM + skcl * 8;
    bS[q] = cbb + (size_t)(k0 + srow) * DDIM + skcl * 8;
  }

  auto stageA = [&](int tile, int h, int b) {
    #pragma unroll
    for (int q = 0; q < 2; ++q)
      gld_lds16(aS[q] + tile * 64 + h * 32,
                (char*)lds + b * 32768 + h * 16384 + ldst[q]);
  };
  auto stageB = [&](int tile, int h, int b) {
    #pragma unroll
    for (int q = 0; q < 2; ++q)
      gld_lds16(bS[q] + tile * 64 + h * 32,
                (char*)lds + 65536 + b * 32768 + h * 16384 + ldst[q]);
  };
  // swizzled read chunk index
  auto aIdx = [&](int b, int h, int row) {
    return b * 2048 + h * 1024 + row * 4 + (l4 ^ ((row >> 1) & 3));
  };
  auto bIdx = [&](int b, int h, int row) {
    return 4096 + b * 2048 + h * 1024 + row * 4 + (l4 ^ ((row >> 1) & 3));
  };

  f32x4 acc[8][4];
  #pragma unroll
  for (int i = 0; i < 8; ++i)
    #pragma unroll
    for (int j = 0; j < 4; ++j) acc[i][j] = (f32x4){0.f, 0.f, 0.f, 0.f};

  // --- prologue: stage tile 0 (4 halves) into buf0; publish h0 halves ---
  stageA(0, 0, 0); stageB(0, 0, 0); stageA(0, 1, 0); stageB(0, 1, 0);
  asm volatile("s_waitcnt vmcnt(4)" ::: "memory");   // A0h0,B0h0 landed
  __builtin_amdgcn_s_barrier();

  s16x8 af[8], b0, b1;

  // --- main loop: tile t from buf (t&1); stage tile t+1 into the other ---
  // Phases per tile: P0{rd A(h0)x8+B(h0,nf01); stage A'}  P1{rd B(h0,nf23); stage B'; vmcnt4}
  //                  P2{rd A(h1)x8+B(h1,nf01); stage A''} P3{rd B(h1,nf23); stage B''; vmcnt4}
  auto ktile = [&](int t, int tn, int b) {
    const int nb = b ^ 1;
    // ---- P0 ----
    #pragma unroll
    for (int f = 0; f < 8; ++f) af[f] = lds[aIdx(b, 0, wm * 128 + f * 16 + l15)];
    b0 = lds[bIdx(b, 0, wn * 64 + 0 * 16 + l15)];
    b1 = lds[bIdx(b, 0, wn * 64 + 1 * 16 + l15)];
    stageA(tn, 0, nb);
    __builtin_amdgcn_s_barrier();
    asm volatile("s_waitcnt lgkmcnt(0)" ::: "memory");
    __builtin_amdgcn_sched_barrier(0);
    __builtin_amdgcn_s_setprio(1);
    #pragma unroll
    for (int f = 0; f < 8; ++f) {
      acc[f][0] = __builtin_amdgcn_mfma_f32_16x16x32_bf16(af[f], b0, acc[f][0], 0, 0, 0);
      acc[f][1] = __builtin_amdgcn_mfma_f32_16x16x32_bf16(af[f], b1, acc[f][1], 0, 0, 0);
    }
    __builtin_amdgcn_s_setprio(0);
    __builtin_amdgcn_s_barrier();
    // ---- P1 ----
    b0 = lds[bIdx(b, 0, wn * 64 + 2 * 16 + l15)];
    b1 = lds[bIdx(b, 0, wn * 64 + 3 * 16 + l15)];
    stageB(tn, 0, nb);
    __builtin_amdgcn_s_barrier();
    asm volatile("s_waitcnt lgkmcnt(0)" ::: "memory");
    __builtin_amdgcn_sched_barrier(0);
    __builtin_amdgcn_s_setprio(1);
    #pragma unroll
    for (int f = 0; f < 8; ++f) {
      acc[f][2] = __builtin_amdgcn_mfma_f32_16x16x32_bf16(af[f], b0, acc[f][2], 0, 0, 0);
      acc[f][3] = __builtin_amdgcn_mfma_f32_16x16x32_bf16(af[f], b1, acc[f][3], 0, 0, 0);
    }
    __builtin_amdgcn_s_setprio(0);
    asm volatile("s_waitcnt vmcnt(4)" ::: "memory");  // publish this tile's h1 halves
    __builtin_amdgcn_s_barrier();
    // ---- P2 ----
    #pragma unroll
    for (int f = 0; f < 8; ++f) af[f] = lds[aIdx(b, 1, wm * 128 + f * 16 + l15)];
    b0 = lds[bIdx(b, 1, wn * 64 + 0 * 16 + l15)];
    b1 = lds[bIdx(b, 1, wn * 64 + 1 * 16 + l15)];
    stageA(tn, 1, nb);
    __builtin_amdgcn_s_barrier();
    asm volatile("s_waitcnt lgkmcnt(0)" ::: "memory");
    __builtin_amdgcn_sched_barrier(0);
    __builtin_amdgcn_s_setprio(1);
    #pragma unroll
    for (int f = 0; f < 8; ++f) {
      acc[f][0] = __builtin_amdgcn_mfma_f32_16x16x32_bf16(af[f], b0, acc[f][0], 0, 0, 0);
      acc[f][1] = __builtin_amdgcn_mfma_f32_16x16x32_bf16(af[f], b1, acc[f][1], 0, 0, 0);
    }
    __builtin_amdgcn_s_setprio(0);
    __builtin_amdgcn_s_barrier();
    // ---- P3 ----
    b0 = lds[bIdx(b, 1, wn * 64 + 2 * 16 + l15)];
    b1 = lds[bIdx(b, 1, wn * 64 + 3 * 16 + l15)];
    stageB(tn, 1, nb);
    __builtin_amdgcn_s_barrier();
    asm volatile("s_waitcnt lgkmcnt(0)" ::: "memory");
    __builtin_amdgcn_sched_barrier(0);
    __builtin_amdgcn_s_setprio(1);
    #pragma unroll
    for (int f = 0; f < 8; ++f) {
      acc[f][2] = __builtin_amdgcn_mfma_f32_16x16x32_bf16(af[f], b0, acc[f][2], 0, 0, 0);
      acc[f][3] = __builtin_amdgcn_mfma_f32_16x16x32_bf16(af[f], b1, acc[f][3], 0, 0, 0);
    }
    __builtin_amdgcn_s_setprio(0);
    asm volatile("s_waitcnt vmcnt(4)" ::: "memory");  // publish next tile's h0 halves
    __builtin_amdgcn_s_barrier();
  };

  #pragma unroll 1
  for (int tt = 0; tt < 8; ++tt) {
    ktile(2 * tt,     2 * tt + 1,                 0);
    ktile(2 * tt + 1, (tt == 7) ? 15 : 2 * tt + 2, 1);
  }

  // --- epilogue: logits + per-(row, block) min table ---
  // C/D layout (16x16x32): col = l15 (code k), row = l4*4 + reg (z-row n)
  float ee[4];
  #pragma unroll
  for (int j = 0; j < 4; ++j) ee[j] = nrm[NROWS + k0 + wn * 64 + j * 16 + l15];

  float* logits = out + LOG_OFF;
  #pragma unroll
  for (int f = 0; f < 8; ++f) {
    #pragma unroll
    for (int r = 0; r < 4; ++r) {
      const int n = n0 + wm * 128 + f * 16 + l4 * 4 + r;
      const float zz = nrm[n];
      float rowmin = 3.4e38f;
      #pragma unroll
      for (int j = 0; j < 4; ++j) {
        const int k = k0 + wn * 64 + j * 16 + l15;
        const float dist = fmaf(-2.f, acc[f][j][r], zz + ee[j]);
        __builtin_nontemporal_store(-dist, &logits[(size_t)n * KCODES + k]);
        rowmin = fminf(rowmin, dist);
      }
      #pragma unroll
      for (int mm = 1; mm < 16; mm <<= 1)
        rowmin = fminf(rowmin, __shfl_xor(rowmin, mm, 64));
      if (l15 == 0) atomicMin(&gmins[(size_t)n * 32 + bx], forder(rowmin));
    }
  }
}

// ---------------------------------------------------------------------------
// Kernel 3: refine — global min from 32-entry table, scan only qualifying
// 256-col groups for candidates, recompute exact fp32 distances, true argmin.
// ---------------------------------------------------------------------------
#define MARGIN 16.0f
__global__ __launch_bounds__(256) void vq_refine(const float* __restrict__ z,
                                                 const float* __restrict__ cb,
                                                 const float* __restrict__ nrm,
                                                 const unsigned int* __restrict__ gmins,
                                                 float* __restrict__ out) {
  const int n = blockIdx.x;
  const int tid = threadIdx.x;
  __shared__ float tminS[32];
  __shared__ float gminS;
  __shared__ int cnt;
  __shared__ int cand[64];
  __shared__ float red[4];

  if (tid < 32) tminS[tid] = finv(gmins[(size_t)n * 32 + tid]);
  if (tid == 0) cnt = 0;
  __syncthreads();
  if (tid == 0) {
    float g = tminS[0];
    #pragma unroll
    for (int i = 1; i < 32; ++i) g = fminf(g, tminS[i]);
    gminS = g;
  }
  __syncthreads();
  const float thr = gminS + MARGIN;

  // candidate collection from qualifying 256-col groups (uniform branch)
  const float* lrow = out + LOG_OFF + (size_t)n * KCODES;
  for (int g = 0; g < 32; ++g) {
    if (tminS[g] <= thr) {
      const float dist = -lrow[g * 256 + tid];
      if (dist <= thr) {
        const int p = atomicAdd(&cnt, 1);
        if (p < 64) cand[p] = g * 256 + tid;
      }
    }
  }
  __syncthreads();
  const int ncand = min(cnt, 64);

  // exact fp32 recompute per candidate
  const float zz = nrm[n];
  const float4 zv = reinterpret_cast<const float4*>(z + (size_t)n * DDIM)[tid];
  float bestd = 0.f;
  int bestk = -1;
  for (int ci = 0; ci < ncand; ++ci) {
    const int k = cand[ci];
    const float4 ev = reinterpret_cast<const float4*>(cb + (size_t)k * DDIM)[tid];
    float s = zv.x * ev.x + zv.y * ev.y + zv.z * ev.z + zv.w * ev.w;
    #pragma unroll
    for (int mm = 32; mm > 0; mm >>= 1) s += __shfl_down(s, mm, 64);
    if ((tid & 63) == 0) red[tid >> 6] = s;
    __syncthreads();
    const float dot = red[0] + red[1] + red[2] + red[3];
    const float dist = zz + nrm[NROWS + k] - 2.0f * dot;
    if (bestk < 0 || dist < bestd || (dist == bestd && k < bestk)) {
      bestd = dist; bestk = k;
    }
    __syncthreads();
  }
  if (tid == 0) out[IDX_OFF + n] = (float)bestk;
}

// ---------------------------------------------------------------------------
// Kernel 4: gather quantized rows (overwrites the bf16 staging area), loss.
// ---------------------------------------------------------------------------
__global__ __launch_bounds__(256) void vq_finalize(const float* __restrict__ cb,
                                                   float* __restrict__ out) {
  const int n = blockIdx.x;
  const int k = (int)out[IDX_OFF + n];
  const float4* src = reinterpret_cast<const float4*>(cb + (size_t)k * DDIM);
  float4* dst = reinterpret_cast<float4*>(out + (size_t)n * DDIM);
  dst[threadIdx.x] = src[threadIdx.x];
  if (threadIdx.x == 0 && n == 0) out[LOSS_OFF] = 0.f;
}

// ---------------------------------------------------------------------------
extern "C" void kernel_launch(void* const* d_in, const int* in_sizes, int n_in,
                              void* d_out, int out_size, void* d_ws, size_t ws_size,
                              hipStream_t stream) {
  const float* z  = (const float*)d_in[0];
  const float* cb = (const float*)d_in[1];
  float* out = (float*)d_out;

  // ws: [0,64KB) fp32 row norms (16384); [64KB, 64KB+1MB) u32 min table (8192x32)
  float* nrm = (float*)d_ws;
  unsigned int* gmins = (unsigned int*)((char*)d_ws + 65536);

  // bf16 staging lives in the out[quantized] region (exact fit)
  __hip_bfloat16* bfbuf = (__hip_bfloat16*)out;
  const __hip_bfloat16* zbf  = bfbuf;
  const __hip_bfloat16* cbbf = bfbuf + (size_t)NROWS * DDIM;

  hipMemsetAsync((char*)d_ws + 65536, 0xFF, (size_t)NROWS * 32 * 4, stream);
  vq_convert<<<NROWS + KCODES, 256, 0, stream>>>(z, cb, bfbuf, nrm);
  dim3 grid(KCODES / 256, NROWS / 256);
  vq_mfma<<<grid, 512, 0, stream>>>(zbf, cbbf, nrm, gmins, out);
  vq_refine<<<NROWS, 256, 0, stream>>>(z, cb, nrm, gmins, out);
  vq_finalize<<<NROWS, 256, 0, stream>>>(cb, out);
}

// Round 4
// 258.995 us; speedup vs baseline: 5.7905x; 1.0762x over previous
//
#include <hip/hip_runtime.h>
#include <hip/hip_bf16.h>
#include <stdint.h>

// Problem constants (B=8, S=1024, D=1024, K=8192)
#define NROWS 8192   // B*S
#define KCODES 8192
#define DDIM 1024

// d_out flat float32 layout (return order: quantized, indices, loss, logits)
#define Q_OFF    0
#define IDX_OFF  8388608
#define LOSS_OFF 8396800
#define LOG_OFF  8396801   // odd -> logits region only 4B-aligned

using f32x4  = __attribute__((ext_vector_type(4))) float;
using s16x8  = __attribute__((ext_vector_type(8))) short;

// Monotone map float <-> uint32 preserving order (for atomicMin argmin tables)
__device__ __forceinline__ unsigned int forder(float f) {
  unsigned int u = __float_as_uint(f);
  return (u & 0x80000000u) ? ~u : (u | 0x80000000u);
}
__device__ __forceinline__ float finv(unsigned int u) {
  return (u & 0x80000000u) ? __uint_as_float(u & 0x7fffffffu) : __uint_as_float(~u);
}

__device__ __forceinline__ void gld_lds16(const void* g, void* l) {
  __builtin_amdgcn_global_load_lds((const __attribute__((address_space(1))) unsigned int*)g,
                                   (__attribute__((address_space(3))) unsigned int*)l,
                                   16, 0, 0);
}

// ---------------------------------------------------------------------------
// Kernel 1: fp32 -> bf16 copies of z (rows 0..8191) and codebook (8192..16383)
// into the out[quantized] region (overwritten by the final gather), plus
// exact fp32 squared row norms into ws.
// ---------------------------------------------------------------------------
__global__ __launch_bounds__(256) void vq_convert(const float* __restrict__ z,
                                                  const float* __restrict__ cb,
                                                  __hip_bfloat16* __restrict__ bfbuf,
                                                  float* __restrict__ nrm) {
  const int r = blockIdx.x;
  const float* src = (r < NROWS) ? (z + (size_t)r * DDIM)
                                 : (cb + (size_t)(r - NROWS) * DDIM);
  float4 v = reinterpret_cast<const float4*>(src)[threadIdx.x];  // 256*4 = 1024
  float vv[4] = {v.x, v.y, v.z, v.w};
  ushort4 p;
  unsigned short us[4];
  #pragma unroll
  for (int j = 0; j < 4; ++j) {
    __hip_bfloat16 b = __float2bfloat16(vv[j]);
    __builtin_memcpy(&us[j], &b, 2);
  }
  p.x = us[0]; p.y = us[1]; p.z = us[2]; p.w = us[3];
  reinterpret_cast<ushort4*>(bfbuf + (size_t)r * DDIM)[threadIdx.x] = p;

  float s = vv[0]*vv[0] + vv[1]*vv[1] + vv[2]*vv[2] + vv[3]*vv[3];
  #pragma unroll
  for (int m = 32; m > 0; m >>= 1) s += __shfl_down(s, m, 64);
  __shared__ float red[4];
  if ((threadIdx.x & 63) == 0) red[threadIdx.x >> 6] = s;
  __syncthreads();
  if (threadIdx.x == 0) nrm[r] = red[0] + red[1] + red[2] + red[3];
}

// ---------------------------------------------------------------------------
// Kernel 2: bf16 MFMA GEMM, 128x128 tile, 4 waves (2x2, each 64x64 out),
// BK=32, 3-buffer LDS ring (48 KB -> 3 blocks/CU), counted vmcnt(4) pipeline
// with ONE barrier per K-step (no vmcnt(0) drain in the main loop).
// XOR chunk swizzle (both-sides: pre-swizzled global source, swizzled read).
// Writes logits = -(zz + ee - 2*dot) and per-(row, 256-col-group) min table.
// ---------------------------------------------------------------------------
__global__ __launch_bounds__(256, 3) void vq_mfma(const __hip_bfloat16* __restrict__ zb,
                                                  const __hip_bfloat16* __restrict__ cbb,
                                                  const float* __restrict__ nrm,
                                                  unsigned int* __restrict__ gmins,
                                                  float* __restrict__ out) {
  // 48 KB: buffer b at chunk b*1024; A chunks [row*4 + c] (512), B at +512.
  __shared__ s16x8 lds[3072];

  const int bx = blockIdx.x;            // k-block 0..63 (128 codes each)
  const int by = blockIdx.y;            // n-block 0..63
  const int k0 = bx * 128, n0 = by * 128;
  const int tid = threadIdx.x;
  const int wid = tid >> 6, lane = tid & 63;
  const int wm = wid >> 1, wn = wid & 1;   // wave grid 2x2; wave out 64x64
  const int l15 = lane & 15, l4 = lane >> 4;

  // staging: per step each thread issues 2 A + 2 B gld_lds16 (16 KB/block/step)
  // chunk id c = (wid*2+q)*64+lane; row=c>>2; stored pos=c&3 holds global chunk
  // (c&3)^((row>>1)&3)  [pre-swizzled source, linear LDS dest]
  const __hip_bfloat16* aS[2];
  const __hip_bfloat16* bS[2];
  int ldst[2];
  #pragma unroll
  for (int q = 0; q < 2; ++q) {
    const int c = (wid * 2 + q) * 64 + lane;
    const int srow = c >> 2;
    const int spos = (c & 3) ^ ((srow >> 1) & 3);
    ldst[q] = (wid * 2 + q) * 1024;     // byte offset within 8 KB half
    aS[q] = zb  + (size_t)(n0 + srow) * DDIM + spos * 8;
    bS[q] = cbb + (size_t)(k0 + srow) * DDIM + spos * 8;
  }

  auto stage = [&](int t, int b) {
    #pragma unroll
    for (int q = 0; q < 2; ++q)
      gld_lds16(aS[q] + t * 32, (char*)lds + b * 16384 + ldst[q]);
    #pragma unroll
    for (int q = 0; q < 2; ++q)
      gld_lds16(bS[q] + t * 32, (char*)lds + b * 16384 + 8192 + ldst[q]);
  };

  f32x4 acc[4][4];
  #pragma unroll
  for (int i = 0; i < 4; ++i)
    #pragma unroll
    for (int j = 0; j < 4; ++j) acc[i][j] = (f32x4){0.f, 0.f, 0.f, 0.f};

  // K-step body: read 8 frags from buf cur, stage step t+2 into buf nxt, MFMA
  auto kbody = [&](int t, int cur, int nxt, bool stg) {
    s16x8 af[4], bf[4];
    #pragma unroll
    for (int f = 0; f < 4; ++f) {
      const int ar = wm * 64 + f * 16 + l15;
      af[f] = lds[cur * 1024 + ar * 4 + (l4 ^ ((ar >> 1) & 3))];
      const int br = wn * 64 + f * 16 + l15;
      bf[f] = lds[cur * 1024 + 512 + br * 4 + (l4 ^ ((br >> 1) & 3))];
    }
    if (stg) stage(t + 2, nxt);
    asm volatile("s_waitcnt lgkmcnt(0)" ::: "memory");
    __builtin_amdgcn_sched_barrier(0);
    __builtin_amdgcn_s_setprio(1);
    #pragma unroll
    for (int fm = 0; fm < 4; ++fm)
      #pragma unroll
      for (int fn = 0; fn < 4; ++fn)
        acc[fm][fn] = __builtin_amdgcn_mfma_f32_16x16x32_bf16(af[fm], bf[fn], acc[fm][fn], 0, 0, 0);
    __builtin_amdgcn_s_setprio(0);
  };

  // prologue: stage steps 0,1 into bufs 0,1; publish buf0
  stage(0, 0);
  stage(1, 1);
  asm volatile("s_waitcnt vmcnt(4)" ::: "memory");
  __builtin_amdgcn_s_barrier();

  // main loop: t = 0..29 (staging t+2 <= 31), counted vmcnt(4), 1 barrier/step
  #pragma unroll 1
  for (int tt = 0; tt < 10; ++tt) {
    const int t = tt * 3;
    kbody(t,     0, 2, true);
    asm volatile("s_waitcnt vmcnt(4)" ::: "memory");
    __builtin_amdgcn_s_barrier();
    kbody(t + 1, 1, 0, true);
    asm volatile("s_waitcnt vmcnt(4)" ::: "memory");
    __builtin_amdgcn_s_barrier();
    kbody(t + 2, 2, 1, true);
    asm volatile("s_waitcnt vmcnt(4)" ::: "memory");
    __builtin_amdgcn_s_barrier();
  }
  // tail: t=30 (wait last stage), t=31
  kbody(30, 0, 2, false);
  asm volatile("s_waitcnt vmcnt(0)" ::: "memory");
  __builtin_amdgcn_s_barrier();
  kbody(31, 1, 0, false);

  // --- epilogue: logits + per-(row, 256-col-group) min table ---
  // C/D layout (16x16x32): col = l15 (code k), row = l4*4 + reg (z-row n)
  float ee[4];
  #pragma unroll
  for (int j = 0; j < 4; ++j) ee[j] = nrm[NROWS + k0 + wn * 64 + j * 16 + l15];

  float* logits = out + LOG_OFF;
  #pragma unroll
  for (int f = 0; f < 4; ++f) {
    #pragma unroll
    for (int r = 0; r < 4; ++r) {
      const int n = n0 + wm * 64 + f * 16 + l4 * 4 + r;
      const float zz = nrm[n];
      float rowmin = 3.4e38f;
      #pragma unroll
      for (int j = 0; j < 4; ++j) {
        const int k = k0 + wn * 64 + j * 16 + l15;
        const float dist = fmaf(-2.f, acc[f][j][r], zz + ee[j]);
        logits[(size_t)n * KCODES + k] = -dist;
        rowmin = fminf(rowmin, dist);
      }
      #pragma unroll
      for (int mm = 1; mm < 16; mm <<= 1)
        rowmin = fminf(rowmin, __shfl_xor(rowmin, mm, 64));
      if (l15 == 0) atomicMin(&gmins[(size_t)n * 32 + (bx >> 1)], forder(rowmin));
    }
  }
}

// ---------------------------------------------------------------------------
// Kernel 3: refine + gather — global min from 32-entry table, scan qualifying
// 256-col groups, recompute exact fp32 distances, true argmin (tie -> min k),
// then gather cb[bestk] into out[quantized] and write index + loss.
// ---------------------------------------------------------------------------
#define MARGIN 16.0f
__global__ __launch_bounds__(256) void vq_refine(const float* __restrict__ z,
                                                 const float* __restrict__ cb,
                                                 const float* __restrict__ nrm,
                                                 const unsigned int* __restrict__ gmins,
                                                 float* __restrict__ out) {
  const int n = blockIdx.x;
  const int tid = threadIdx.x;
  __shared__ float tminS[32];
  __shared__ float gminS;
  __shared__ int cnt;
  __shared__ int cand[64];
  __shared__ float red[4];

  if (tid < 32) tminS[tid] = finv(gmins[(size_t)n * 32 + tid]);
  if (tid == 0) cnt = 0;
  __syncthreads();
  if (tid == 0) {
    float g = tminS[0];
    #pragma unroll
    for (int i = 1; i < 32; ++i) g = fminf(g, tminS[i]);
    gminS = g;
  }
  __syncthreads();
  const float thr = gminS + MARGIN;

  // candidate collection from qualifying 256-col groups (uniform branch)
  const float* lrow = out + LOG_OFF + (size_t)n * KCODES;
  for (int g = 0; g < 32; ++g) {
    if (tminS[g] <= thr) {
      const float dist = -lrow[g * 256 + tid];
      if (dist <= thr) {
        const int p = atomicAdd(&cnt, 1);
        if (p < 64) cand[p] = g * 256 + tid;
      }
    }
  }
  __syncthreads();
  const int ncand = min(cnt, 64);

  // exact fp32 recompute per candidate (all threads compute identical best)
  const float zz = nrm[n];
  const float4 zv = reinterpret_cast<const float4*>(z + (size_t)n * DDIM)[tid];
  float bestd = 0.f;
  int bestk = -1;
  for (int ci = 0; ci < ncand; ++ci) {
    const int k = cand[ci];
    const float4 ev = reinterpret_cast<const float4*>(cb + (size_t)k * DDIM)[tid];
    float s = zv.x * ev.x + zv.y * ev.y + zv.z * ev.z + zv.w * ev.w;
    #pragma unroll
    for (int mm = 32; mm > 0; mm >>= 1) s += __shfl_down(s, mm, 64);
    if ((tid & 63) == 0) red[tid >> 6] = s;
    __syncthreads();
    const float dot = red[0] + red[1] + red[2] + red[3];
    const float dist = zz + nrm[NROWS + k] - 2.0f * dot;
    if (bestk < 0 || dist < bestd || (dist == bestd && k < bestk)) {
      bestd = dist; bestk = k;
    }
    __syncthreads();
  }

  // fused gather: every thread agrees on bestk (>=0 guaranteed: the approx
  // argmin itself satisfies dist == gmin <= thr)
  const float4* src = reinterpret_cast<const float4*>(cb + (size_t)bestk * DDIM);
  float4* dst = reinterpret_cast<float4*>(out + (size_t)n * DDIM);
  dst[tid] = src[tid];
  if (tid == 0) {
    out[IDX_OFF + n] = (float)bestk;
    if (n == 0) out[LOSS_OFF] = 0.f;
  }
}

// ---------------------------------------------------------------------------
extern "C" void kernel_launch(void* const* d_in, const int* in_sizes, int n_in,
                              void* d_out, int out_size, void* d_ws, size_t ws_size,
                              hipStream_t stream) {
  const float* z  = (const float*)d_in[0];
  const float* cb = (const float*)d_in[1];
  float* out = (float*)d_out;

  // ws: [0,64KB) fp32 row norms (16384); [64KB, 64KB+1MB) u32 min table (8192x32)
  float* nrm = (float*)d_ws;
  unsigned int* gmins = (unsigned int*)((char*)d_ws + 65536);

  // bf16 staging lives in the out[quantized] region (exact fit, overwritten
  // afterwards by the refine kernel's fused gather)
  __hip_bfloat16* bfbuf = (__hip_bfloat16*)out;
  const __hip_bfloat16* zbf  = bfbuf;
  const __hip_bfloat16* cbbf = bfbuf + (size_t)NROWS * DDIM;

  hipMemsetAsync((char*)d_ws + 65536, 0xFF, (size_t)NROWS * 32 * 4, stream);
  vq_convert<<<NROWS + KCODES, 256, 0, stream>>>(z, cb, bfbuf, nrm);
  dim3 grid(KCODES / 128, NROWS / 128);
  vq_mfma<<<grid, 256, 0, stream>>>(zbf, cbbf, nrm, gmins, out);
  vq_refine<<<NROWS, 256, 0, stream>>>(z, cb, nrm, gmins, out);
}

// Round 5
// 231.396 us; speedup vs baseline: 6.4812x; 1.1193x over previous
//
#include <hip/hip_runtime.h>
#include <hip/hip_bf16.h>
#include <stdint.h>

// Problem constants (B=8, S=1024, D=1024, K=8192)
#define NROWS 8192   // B*S
#define KCODES 8192
#define DDIM 1024

// d_out flat float32 layout (return order: quantized, indices, loss, logits)
#define Q_OFF    0
#define IDX_OFF  8388608
#define LOSS_OFF 8396800
#define LOG_OFF  8396801   // odd -> logits region only 4B-aligned

using f32x4  = __attribute__((ext_vector_type(4))) float;
using s16x8  = __attribute__((ext_vector_type(8))) short;

// Monotone map float <-> uint32 preserving order (for atomicMin argmin tables)
__device__ __forceinline__ unsigned int forder(float f) {
  unsigned int u = __float_as_uint(f);
  return (u & 0x80000000u) ? ~u : (u | 0x80000000u);
}
__device__ __forceinline__ float finv(unsigned int u) {
  return (u & 0x80000000u) ? __uint_as_float(u & 0x7fffffffu) : __uint_as_float(~u);
}

__device__ __forceinline__ void gld_lds16(const void* g, void* l) {
  __builtin_amdgcn_global_load_lds((const __attribute__((address_space(1))) unsigned int*)g,
                                   (__attribute__((address_space(3))) unsigned int*)l,
                                   16, 0, 0);
}

// ---------------------------------------------------------------------------
// Kernel 1: fp32 -> bf16 copies of z (rows 0..8191) and codebook (8192..16383)
// into the out[quantized] region (overwritten by the final gather), plus
// exact fp32 squared row norms into ws.
// ---------------------------------------------------------------------------
__global__ __launch_bounds__(256) void vq_convert(const float* __restrict__ z,
                                                  const float* __restrict__ cb,
                                                  __hip_bfloat16* __restrict__ bfbuf,
                                                  float* __restrict__ nrm) {
  const int r = blockIdx.x;
  const float* src = (r < NROWS) ? (z + (size_t)r * DDIM)
                                 : (cb + (size_t)(r - NROWS) * DDIM);
  float4 v = reinterpret_cast<const float4*>(src)[threadIdx.x];  // 256*4 = 1024
  float vv[4] = {v.x, v.y, v.z, v.w};
  ushort4 p;
  unsigned short us[4];
  #pragma unroll
  for (int j = 0; j < 4; ++j) {
    __hip_bfloat16 b = __float2bfloat16(vv[j]);
    __builtin_memcpy(&us[j], &b, 2);
  }
  p.x = us[0]; p.y = us[1]; p.z = us[2]; p.w = us[3];
  reinterpret_cast<ushort4*>(bfbuf + (size_t)r * DDIM)[threadIdx.x] = p;

  float s = vv[0]*vv[0] + vv[1]*vv[1] + vv[2]*vv[2] + vv[3]*vv[3];
  #pragma unroll
  for (int m = 32; m > 0; m >>= 1) s += __shfl_down(s, m, 64);
  __shared__ float red[4];
  if ((threadIdx.x & 63) == 0) red[threadIdx.x >> 6] = s;
  __syncthreads();
  if (threadIdx.x == 0) nrm[r] = red[0] + red[1] + red[2] + red[3];
}

// ---------------------------------------------------------------------------
// Kernel 2: bf16 MFMA GEMM, 128x128 tile, BK=64, 4 waves (each 64x64 out) —
// the proven round-2 body — plus XCD-aware supertile swizzle:
//   xcd = wgid&7 selects a fixed 8-k-block band (B slice 2MB -> pinned in that
//   XCD's private L2); all XCDs walk A panels (sty) in lockstep -> L3-served.
// Writes logits = -(zz + ee - 2*dot) and per-(row, 256-col-group) min table.
// ---------------------------------------------------------------------------
__global__ __launch_bounds__(256, 3) void vq_mfma(const __hip_bfloat16* __restrict__ zb,
                                                  const __hip_bfloat16* __restrict__ cbb,
                                                  const float* __restrict__ nrm,
                                                  unsigned int* __restrict__ gmins,
                                                  float* __restrict__ out) {
  __shared__ s16x8 Asv[1024];  // 128 rows x 8 chunks of 8 bf16 (16KB)
  __shared__ s16x8 Bsv[1024];

  // --- XCD supertile swizzle (8x8 blocks per supertile) ---
  const int wgid = blockIdx.x;         // 0..4095
  const int stx = wgid & 7;            // XCD id (round-robin dispatch heuristic)
  const int idx = wgid >> 3;           // 0..511 within XCD
  const int sty = idx >> 6;            // 0..7: A-panel row, lockstep across XCDs
  const int tt_ = idx & 63;
  const int bx = stx * 8 + (tt_ & 7);  // k-block 0..63
  const int by = sty * 8 + (tt_ >> 3); // n-block 0..63

  const int k0 = bx * 128;
  const int n0 = by * 128;
  const int tid = threadIdx.x;
  const int wid = tid >> 6, lane = tid & 63;
  const int wm = wid >> 1, wn = wid & 1;    // wave grid 2x2, wave out = 64x64
  const int l15 = lane & 15, l4 = lane >> 4;

  // staging geometry: slab s = wid*4+q covers rows 8s..8s+7 (1KB per wave-issue)
  const int srow = lane >> 3;          // row within slab
  const int c    = lane & 7;           // LDS 16B chunk within row
  const __hip_bfloat16* ga[4];
  const __hip_bfloat16* gb[4];
  int loff[4];
  #pragma unroll
  for (int q = 0; q < 4; ++q) {
    const int s = wid * 4 + q;
    const int row = s * 8 + srow;
    const int cg = c ^ (row & 7);      // pre-swizzled global chunk
    ga[q] = zb  + (size_t)(n0 + row) * DDIM + cg * 8;
    gb[q] = cbb + (size_t)(k0 + row) * DDIM + cg * 8;
    loff[q] = s * 1024;                // LDS byte offset of slab (wave-uniform)
  }

  f32x4 acc[4][4];
  #pragma unroll
  for (int i = 0; i < 4; ++i)
    #pragma unroll
    for (int j = 0; j < 4; ++j) acc[i][j] = (f32x4){0.f, 0.f, 0.f, 0.f};

  for (int it = 0; it < 16; ++it) {
    const int d0 = it * 64;
    #pragma unroll
    for (int q = 0; q < 4; ++q) {
      gld_lds16(ga[q] + d0, (char*)Asv + loff[q]);
      gld_lds16(gb[q] + d0, (char*)Bsv + loff[q]);
    }
    __syncthreads();  // compiler drains vmcnt before barrier -> tile staged

    #pragma unroll
    for (int ks = 0; ks < 2; ++ks) {
      const int ch = ks * 4 + l4;      // wanted global chunk 0..7
      s16x8 af[4], bf[4];
      #pragma unroll
      for (int f = 0; f < 4; ++f) {
        const int ar = wm * 64 + f * 16 + l15;
        af[f] = Asv[ar * 8 + (ch ^ (ar & 7))];
        const int br = wn * 64 + f * 16 + l15;
        bf[f] = Bsv[br * 8 + (ch ^ (br & 7))];
      }
      #pragma unroll
      for (int fm = 0; fm < 4; ++fm)
        #pragma unroll
        for (int fn = 0; fn < 4; ++fn)
          acc[fm][fn] = __builtin_amdgcn_mfma_f32_16x16x32_bf16(af[fm], bf[fn], acc[fm][fn], 0, 0, 0);
    }
    __syncthreads();  // readers done before next overwrite
  }

  // --- epilogue: logits + per-(row, 256-col-group) min table ---
  // C/D layout (16x16x32): col = l15 (code k), row = l4*4 + reg (z-row n)
  float ee[4];
  #pragma unroll
  for (int j = 0; j < 4; ++j) ee[j] = nrm[NROWS + k0 + wn * 64 + j * 16 + l15];

  float* logits = out + LOG_OFF;
  #pragma unroll
  for (int f = 0; f < 4; ++f) {
    #pragma unroll
    for (int r = 0; r < 4; ++r) {
      const int n = n0 + wm * 64 + f * 16 + l4 * 4 + r;
      const float zz = nrm[n];
      float rowmin = 3.4e38f;
      #pragma unroll
      for (int j = 0; j < 4; ++j) {
        const int k = k0 + wn * 64 + j * 16 + l15;
        const float dist = fmaf(-2.f, acc[f][j][r], zz + ee[j]);
        logits[(size_t)n * KCODES + k] = -dist;
        rowmin = fminf(rowmin, dist);
      }
      #pragma unroll
      for (int mm = 1; mm < 16; mm <<= 1)
        rowmin = fminf(rowmin, __shfl_xor(rowmin, mm, 64));
      if (l15 == 0) atomicMin(&gmins[(size_t)n * 32 + (bx >> 1)], forder(rowmin));
    }
  }
}

// ---------------------------------------------------------------------------
// Kernel 3: refine + gather — global min from 32-entry table, scan qualifying
// 256-col groups, recompute exact fp32 distances, true argmin (tie -> min k),
// then gather cb[bestk] into out[quantized] and write index + loss.
// ---------------------------------------------------------------------------
#define MARGIN 16.0f
__global__ __launch_bounds__(256) void vq_refine(const float* __restrict__ z,
                                                 const float* __restrict__ cb,
                                                 const float* __restrict__ nrm,
                                                 const unsigned int* __restrict__ gmins,
                                                 float* __restrict__ out) {
  const int n = blockIdx.x;
  const int tid = threadIdx.x;
  __shared__ float tminS[32];
  __shared__ float gminS;
  __shared__ int cnt;
  __shared__ int cand[64];
  __shared__ float red[4];

  if (tid < 32) tminS[tid] = finv(gmins[(size_t)n * 32 + tid]);
  if (tid == 0) cnt = 0;
  __syncthreads();
  if (tid == 0) {
    float g = tminS[0];
    #pragma unroll
    for (int i = 1; i < 32; ++i) g = fminf(g, tminS[i]);
    gminS = g;
  }
  __syncthreads();
  const float thr = gminS + MARGIN;

  // candidate collection from qualifying 256-col groups (uniform branch)
  const float* lrow = out + LOG_OFF + (size_t)n * KCODES;
  for (int g = 0; g < 32; ++g) {
    if (tminS[g] <= thr) {
      const float dist = -lrow[g * 256 + tid];
      if (dist <= thr) {
        const int p = atomicAdd(&cnt, 1);
        if (p < 64) cand[p] = g * 256 + tid;
      }
    }
  }
  __syncthreads();
  const int ncand = min(cnt, 64);

  // exact fp32 recompute per candidate (all threads compute identical best)
  const float zz = nrm[n];
  const float4 zv = reinterpret_cast<const float4*>(z + (size_t)n * DDIM)[tid];
  float bestd = 0.f;
  int bestk = -1;
  for (int ci = 0; ci < ncand; ++ci) {
    const int k = cand[ci];
    const float4 ev = reinterpret_cast<const float4*>(cb + (size_t)k * DDIM)[tid];
    float s = zv.x * ev.x + zv.y * ev.y + zv.z * ev.z + zv.w * ev.w;
    #pragma unroll
    for (int mm = 32; mm > 0; mm >>= 1) s += __shfl_down(s, mm, 64);
    if ((tid & 63) == 0) red[tid >> 6] = s;
    __syncthreads();
    const float dot = red[0] + red[1] + red[2] + red[3];
    const float dist = zz + nrm[NROWS + k] - 2.0f * dot;
    if (bestk < 0 || dist < bestd || (dist == bestd && k < bestk)) {
      bestd = dist; bestk = k;
    }
    __syncthreads();
  }

  // fused gather: every thread agrees on bestk (>=0 guaranteed: the approx
  // argmin's own group qualifies and its dist == gmin <= thr)
  const float4* src = reinterpret_cast<const float4*>(cb + (size_t)bestk * DDIM);
  float4* dst = reinterpret_cast<float4*>(out + (size_t)n * DDIM);
  dst[tid] = src[tid];
  if (tid == 0) {
    out[IDX_OFF + n] = (float)bestk;
    if (n == 0) out[LOSS_OFF] = 0.f;
  }
}

// ---------------------------------------------------------------------------
extern "C" void kernel_launch(void* const* d_in, const int* in_sizes, int n_in,
                              void* d_out, int out_size, void* d_ws, size_t ws_size,
                              hipStream_t stream) {
  const float* z  = (const float*)d_in[0];
  const float* cb = (const float*)d_in[1];
  float* out = (float*)d_out;

  // ws: [0,64KB) fp32 row norms (16384); [64KB, 64KB+1MB) u32 min table (8192x32)
  float* nrm = (float*)d_ws;
  unsigned int* gmins = (unsigned int*)((char*)d_ws + 65536);

  // bf16 staging lives in the out[quantized] region (exact fit, overwritten
  // afterwards by the refine kernel's fused gather)
  __hip_bfloat16* bfbuf = (__hip_bfloat16*)out;
  const __hip_bfloat16* zbf  = bfbuf;
  const __hip_bfloat16* cbbf = bfbuf + (size_t)NROWS * DDIM;

  hipMemsetAsync((char*)d_ws + 65536, 0xFF, (size_t)NROWS * 32 * 4, stream);
  vq_convert<<<NROWS + KCODES, 256, 0, stream>>>(z, cb, bfbuf, nrm);
  vq_mfma<<<4096, 256, 0, stream>>>(zbf, cbbf, nrm, gmins, out);
  vq_refine<<<NROWS, 256, 0, stream>>>(z, cb, nrm, gmins, out);
}